// Round 1
// baseline (330.617 us; speedup 1.0000x reference)
//
#include <hip/hip_runtime.h>
#include <hip/hip_bf16.h>
#include <math.h>

#define S_LEN   4096
#define B_SZ    32
#define D_DIM   64
#define L_LNK   13
#define NW_R    13
#define HF_W    128
#define HV_W    128
#define VOCAB_N 512
#define NC_N    2

__device__ __forceinline__ float gelu_erf(float x) {
    return 0.5f * x * (1.0f + erff(x * 0.70710678118654752440f));
}

__device__ __forceinline__ void fma4(float4& a, float s, float4 z) {
    a.x += s * z.x; a.y += s * z.y; a.z += s * z.z; a.w += s * z.w;
}

// ---------------------------------------------------------------------------
// Kernel A: per-token tables.
//   F_table[k, t, 0..12] = gelu(emb[t] @ fW1[k] + fb1[k]) @ fW2[k] + fb2[k]
//   (padded to 16 floats/row for aligned float4 loads; cols 13..15 = 0)
//   V_table[t, :]        = gelu(emb[t] @ vW1 + vb1) @ vW2 + vb2
// Grid: 13*512 F-blocks then 512 V-blocks, 128 threads each.
// ---------------------------------------------------------------------------
__global__ __launch_bounds__(128)
void tables_kernel(const float* __restrict__ emb,
                   const float* __restrict__ fW1, const float* __restrict__ fb1,
                   const float* __restrict__ fW2, const float* __restrict__ fb2,
                   const float* __restrict__ vW1, const float* __restrict__ vb1,
                   const float* __restrict__ vW2, const float* __restrict__ vb2,
                   float* __restrict__ F_table, float* __restrict__ V_table) {
    __shared__ float s_emb[D_DIM];
    __shared__ float s_H[HF_W];
    const int blk = blockIdx.x;
    const int tid = threadIdx.x;

    if (blk < NW_R * VOCAB_N) {
        const int k = blk >> 9;          // / 512
        const int t = blk & (VOCAB_N - 1);
        if (tid < D_DIM) s_emb[tid] = emb[t * D_DIM + tid];
        __syncthreads();
        float acc = fb1[k * HF_W + tid];
        const float* w = fW1 + (size_t)k * D_DIM * HF_W + tid;
        #pragma unroll 8
        for (int d = 0; d < D_DIM; ++d) acc += s_emb[d] * w[d * HF_W];
        s_H[tid] = gelu_erf(acc);
        __syncthreads();
        if (tid < 16) {
            float o = 0.0f;
            if (tid < L_LNK) {
                o = fb2[k * L_LNK + tid];
                const float* w2 = fW2 + (size_t)k * HF_W * L_LNK + tid;
                #pragma unroll 8
                for (int h = 0; h < HF_W; ++h) o += s_H[h] * w2[h * L_LNK];
            }
            F_table[((size_t)(k * VOCAB_N + t)) * 16 + tid] = o;
        }
    } else {
        const int t = blk - NW_R * VOCAB_N;
        if (tid < D_DIM) s_emb[tid] = emb[t * D_DIM + tid];
        __syncthreads();
        float acc = vb1[tid];
        const float* w = vW1 + tid;
        #pragma unroll 8
        for (int d = 0; d < D_DIM; ++d) acc += s_emb[d] * w[d * HV_W];
        s_H[tid] = gelu_erf(acc);
        __syncthreads();
        if (tid < D_DIM) {
            float o = vb2[tid];
            const float* w2 = vW2 + tid;
            #pragma unroll 8
            for (int h = 0; h < HV_W; ++h) o += s_H[h] * w2[h * D_DIM];
            V_table[t * D_DIM + tid] = o;
        }
    }
}

// ---------------------------------------------------------------------------
// Kernel B: out[b,c] = finb[c] + sum_s V_table[tok[b,s]] . finW[c, s*64:(s+1)*64]
// Grid: B*NC = 64 blocks x 256 threads.
// ---------------------------------------------------------------------------
__global__ __launch_bounds__(256)
void logits_kernel(const int* __restrict__ tok,
                   const float* __restrict__ V_table,
                   const float* __restrict__ finW,
                   const float* __restrict__ finb,
                   float* __restrict__ out) {
    const int b = blockIdx.x >> 1;
    const int c = blockIdx.x & 1;
    const int tid = threadIdx.x;
    const float4* fin4 = (const float4*)(finW + (size_t)c * S_LEN * D_DIM);
    const float4* V4 = (const float4*)V_table;
    float acc = 0.0f;
    for (int s = tid; s < S_LEN; s += 256) {
        const int t = tok[b * S_LEN + s];
        const float4* vp = V4 + t * 16;
        const float4* fp = fin4 + s * 16;
        #pragma unroll
        for (int j = 0; j < 16; ++j) {
            float4 v = vp[j], f = fp[j];
            acc += v.x * f.x + v.y * f.y + v.z * f.z + v.w * f.w;
        }
    }
    #pragma unroll
    for (int o = 32; o > 0; o >>= 1) acc += __shfl_down(acc, o, 64);
    __shared__ float s_part[4];
    if ((tid & 63) == 0) s_part[tid >> 6] = acc;
    __syncthreads();
    if (tid == 0)
        out[b * NC_N + c] = s_part[0] + s_part[1] + s_part[2] + s_part[3] + finb[c];
}

// ---------------------------------------------------------------------------
// Kernel C: chord sparse-multiply, Z LDS-resident.
// One block = (batch b, 4-dim slice ds). Zs = 4096 rows x float4 = 64 KB LDS.
// 13 rounds; per row 13 links: link-0 term from registers (zprev), links
// 1..12 from LDS at offsets 2^l; residual V kept in registers.
// Grid: dim3(16, 32), 1024 threads; thread t owns rows t, t+1024, t+2048, t+3072.
// ---------------------------------------------------------------------------
__global__ __launch_bounds__(1024)
void chord_kernel(const int* __restrict__ tok,
                  const float* __restrict__ F_table,
                  const float* __restrict__ V_table,
                  float* __restrict__ Zout) {
    __shared__ float4 Zs[S_LEN];   // 65536 bytes
    const int b = blockIdx.y;
    const int ds = blockIdx.x;     // dim slice: dims [ds*4, ds*4+4)
    const int t = threadIdx.x;
    const float4* V4 = (const float4*)V_table;

    int tokr[4];
    float4 Vr[4], zprev[4];
    #pragma unroll
    for (int j = 0; j < 4; ++j) {
        const int r = t + 1024 * j;
        const int tk = tok[b * S_LEN + r];
        tokr[j] = tk;
        float4 v = V4[tk * 16 + ds];
        Vr[j] = v;
        zprev[j] = v;
        Zs[r] = v;
    }
    __syncthreads();

    for (int k = 0; k < NW_R; ++k) {
        float4 acc[4];
        #pragma unroll
        for (int j = 0; j < 4; ++j) {
            const int r = t + 1024 * j;
            const float4* F4 =
                (const float4*)(F_table + ((size_t)(k * VOCAB_N + tokr[j]) << 4));
            float4 f0 = F4[0], f1 = F4[1], f2 = F4[2];
            float f12 = ((const float*)F4)[12];

            float4 a = Vr[j];                 // residual pre-added
            fma4(a, f0.x, zprev[j]);          // offset 0: own row, in registers
            fma4(a, f0.y, Zs[(r + 1)    & 4095]);
            fma4(a, f0.z, Zs[(r + 2)    & 4095]);
            fma4(a, f0.w, Zs[(r + 4)    & 4095]);
            fma4(a, f1.x, Zs[(r + 8)    & 4095]);
            fma4(a, f1.y, Zs[(r + 16)   & 4095]);
            fma4(a, f1.z, Zs[(r + 32)   & 4095]);
            fma4(a, f1.w, Zs[(r + 64)   & 4095]);
            fma4(a, f2.x, Zs[(r + 128)  & 4095]);
            fma4(a, f2.y, Zs[(r + 256)  & 4095]);
            fma4(a, f2.z, Zs[(r + 512)  & 4095]);
            fma4(a, f2.w, Zs[(r + 1024) & 4095]);
            fma4(a, f12,  Zs[(r + 2048) & 4095]);
            acc[j] = a;
        }
        __syncthreads();
        if (k < NW_R - 1) {
            #pragma unroll
            for (int j = 0; j < 4; ++j) Zs[t + 1024 * j] = acc[j];
        }
        #pragma unroll
        for (int j = 0; j < 4; ++j) zprev[j] = acc[j];
        __syncthreads();
    }

    float4* Zo = (float4*)Zout;
    #pragma unroll
    for (int j = 0; j < 4; ++j) {
        const int r = t + 1024 * j;
        Zo[((size_t)b * S_LEN + r) * 16 + ds] = zprev[j];
    }
}

extern "C" void kernel_launch(void* const* d_in, const int* in_sizes, int n_in,
                              void* d_out, int out_size, void* d_ws, size_t ws_size,
                              hipStream_t stream) {
    const int*   tok  = (const int*)d_in[0];
    const float* emb  = (const float*)d_in[1];
    const float* fW1  = (const float*)d_in[2];
    const float* fb1  = (const float*)d_in[3];
    const float* fW2  = (const float*)d_in[4];
    const float* fb2  = (const float*)d_in[5];
    const float* vW1  = (const float*)d_in[6];
    const float* vb1  = (const float*)d_in[7];
    const float* vW2  = (const float*)d_in[8];
    const float* vb2  = (const float*)d_in[9];
    const float* finW = (const float*)d_in[10];
    const float* finb = (const float*)d_in[11];

    float* out = (float*)d_out;          // (B, NC) = 64 floats
    float* Z   = out + B_SZ * NC_N;      // (B, S, D) fp32

    // workspace: V_table (512*64 f32 = 128 KB) then F_table (13*512*16 f32 = 416 KB)
    float* V_table = (float*)d_ws;
    float* F_table = V_table + VOCAB_N * D_DIM;

    tables_kernel<<<NW_R * VOCAB_N + VOCAB_N, 128, 0, stream>>>(
        emb, fW1, fb1, fW2, fb2, vW1, vb1, vW2, vb2, F_table, V_table);
    logits_kernel<<<B_SZ * NC_N, 256, 0, stream>>>(tok, V_table, finW, finb, out);
    chord_kernel<<<dim3(16, B_SZ), 1024, 0, stream>>>(tok, F_table, V_table, Z);
}